// Round 5
// baseline (488.430 us; speedup 1.0000x reference)
//
#include <hip/hip_runtime.h>
#include <cstdint>

// MemNet, fully fused, minimal producer->consumer sync, fence-free:
// Q[b,l,j] = v_loc[b,l] * (mem[b,l] . M_j),  25+3 projection columns:
//   col 0        : w0 = w_attn[0:D]
//   col 1+k      : U_k = W_lin^k u, k=0..5   (u = w_attn[D:2D])
//   col 7+6c+k   : Y_{k,c} = W_lin^k W_out[:,c], k=0..5
//   col 25+c     : Y_{6,c}  (hop phase only)
// All shared Mt/Mc/Q locations are WRITE-ONCE, written via agent-scope
// relaxed atomic stores (write-through to the coherent point / IC, no L2
// dirty copies). No location is read before its write inside the dispatch
// (prior fill dispatch's L2 lines are invalidated at kernel boundary), so
// no acquire/invalidate fences anywhere. Flag ordering: __syncthreads
// before each flag add drains vmcnt (write-through stores complete at IC)
// -> RELAXED fetch_add suffices; consumers' data loads are control-
// dependent on the relaxed spin (in-order issue) -> no acquire needed.
// Phases: chain (64 blocks, ticket mini-barriers) || emb prefetch (others,
// 16 loads in flight per wave) -> wait chain step5 -> gemm (tile=bid)
// -> per-batch release -> hop blocks (448..511) wait 8 producers + step6.
// 512 blocks x 256 threads, 2 blocks/CU (LDS 59392 B, lb(256,2)); spins
// are guard-bounded (fail loud, never hang). Epoch = g_ep ticket / 512.

#define DD 1024
#define LL 512
#define MTS 32
#define NCHAIN 64u

__device__ unsigned g_ep;       // +512 per launch
__device__ unsigned g_c[8];     // chain step arrivals: +64 per launch each
__device__ unsigned g_q[64];    // per-batch Q-ready: +8 per launch each

__device__ __forceinline__ void waitge(unsigned* p, unsigned tgt)
{
  int guard = 0;
  while (__hip_atomic_load(p, __ATOMIC_RELAXED, __HIP_MEMORY_SCOPE_AGENT) < tgt) {
    __builtin_amdgcn_s_sleep(2);
    if (++guard > (1 << 19)) break;   // fail loud, never hang
  }
}

// write-through (agent scope) store: lands at the coherent point (IC)
__device__ __forceinline__ void stg(float* p, float v) {
  __hip_atomic_store(p, v, __ATOMIC_RELAXED, __HIP_MEMORY_SCOPE_AGENT);
}

__device__ __forceinline__ void chain_bar(int k)
{
  __syncthreads();   // drains vmcnt: all write-through stores at IC
  if (threadIdx.x == 0) {
    unsigned t = __hip_atomic_fetch_add(&g_c[k], 1u, __ATOMIC_RELAXED,
                                        __HIP_MEMORY_SCOPE_AGENT);
    waitge(&g_c[k], (t / NCHAIN + 1u) * NCHAIN);
  }
  __syncthreads();
}

union SMem {
  struct { float stag[4][64 * 33]; float qp[4][64][25]; } g;        // 59392 B
  struct { float Qs[25 * LL]; float va[DD]; float red[36 * 4]; } h; // 55872 B
};

__device__ __forceinline__ void keep4(float4 v) {
  asm volatile("" :: "v"(v.x), "v"(v.y), "v"(v.z), "v"(v.w));
}

// warm one 64-row tile (256 KB) of gathered embeddings into L2/IC.
// 16 loads in flight per wave (asm keeps OUTSIDE the load batch: the
// volatile asm is a sched boundary, so keep4-inside-loop would serialize
// loads to MLP=1 -- that was round 4's 565 GB/s bug).
__device__ __forceinline__ void prefetch_tile(const int* __restrict__ ctx_ids,
                                              const float* __restrict__ emb,
                                              int tile, int tid)
{
  int ln = tid & 63;
  int myid = ctx_ids[tile * 64 + ln];
#pragma unroll
  for (int g = 0; g < 4; ++g) {
    float4 v[16];
#pragma unroll
    for (int rr = 0; rr < 16; ++rr) {
      int rid = __shfl(myid, g * 16 + rr, 64);
      v[rr] = ((const float4*)(emb + (size_t)rid * DD))[tid];
    }
#pragma unroll
    for (int rr = 0; rr < 16; ++rr) keep4(v[rr]);
  }
}

template <bool ISMAX>
__device__ __forceinline__ void breduce(float* v, int n, float* lds, int tid)
{
  int wv = __builtin_amdgcn_readfirstlane(tid >> 6);
  int ln = tid & 63;
  for (int q = 0; q < n; ++q) {
    float x = v[q];
#pragma unroll
    for (int m = 1; m < 64; m <<= 1) {
      float o = __shfl_xor(x, m, 64);
      x = ISMAX ? fmaxf(x, o) : x + o;
    }
    if (ln == 0) lds[q * 4 + wv] = x;
  }
  __syncthreads();
  for (int q = 0; q < n; ++q) {
    float a = lds[q * 4 + 0], b = lds[q * 4 + 1];
    float c = lds[q * 4 + 2], d = lds[q * 4 + 3];
    v[q] = ISMAX ? fmaxf(fmaxf(a, b), fmaxf(c, d)) : ((a + b) + (c + d));
  }
  __syncthreads();
}

__global__ __launch_bounds__(256, 2) void k_all(
    const int* __restrict__ ctx_ids, const int* __restrict__ tgt_ids,
    const int* __restrict__ ctx_len, const int* __restrict__ tgt_len,
    const int* __restrict__ toff,    const float* __restrict__ emb,
    const float* __restrict__ Wl,    const float* __restrict__ bl,
    const float* __restrict__ wat,   const float* __restrict__ bat,
    const float* __restrict__ bo,    const float* __restrict__ Wo,
    float* __restrict__ Mt, float* __restrict__ Mc,
    float* __restrict__ Q,  float* __restrict__ out)
{
  __shared__ SMem sm;
  const int tid = threadIdx.x;
  const int bid = blockIdx.x;
  const int wv  = __builtin_amdgcn_readfirstlane(tid >> 6);
  const int ln  = tid & 63;
  const int rowbase = bid * 64;

  unsigned E = 0;
  if (tid == 0)
    E = __hip_atomic_fetch_add(&g_ep, 1u, __ATOMIC_RELAXED,
                               __HIP_MEMORY_SCOPE_AGENT) / 512u;

  if (bid < (int)NCHAIN) {
    // ---------- chain: init base columns, then 6 matvec steps -----------
    if (tid < 16) {
      int d = bid * 16 + tid;
      float w0 = wat[d], u0 = wat[DD + d];
      stg(&Mt[d * MTS + 0], w0); stg(&Mc[0 * DD + d], w0);
      stg(&Mt[d * MTS + 1], u0); stg(&Mc[1 * DD + d], u0);
#pragma unroll
      for (int c = 0; c < 3; ++c) {
        float y = Wo[d * 3 + c];
        int col = 7 + 6 * c;
        stg(&Mt[d * MTS + col], y); stg(&Mc[col * DD + d], y);
      }
    }
    chain_bar(0);
    int g    = bid * 256 + tid;     // [0, 16384)
    int q    = g & 3;               // column group: 0=U, 1..3=Y_{c=q-1}
    int part = (g >> 2) & 3;        // j-slice [part*256, part*256+256)
    int row  = g >> 4;              // [0, 1024)
    const float* wr0 = Wl + (size_t)row * DD + part * 256;
    for (int s = 1; s <= 6; ++s) {
      int cin = (q == 0) ? s : q * 6 + s;
      const float* mc = Mc + (size_t)cin * DD + part * 256;
      float4 a4 = {0.f, 0.f, 0.f, 0.f};
#pragma unroll 8
      for (int j = 0; j < 256; j += 4) {
        float4 w = *(const float4*)(wr0 + j);
        float4 m = *(const float4*)(mc + j);
        a4.x += w.x * m.x; a4.y += w.y * m.y;
        a4.z += w.z * m.z; a4.w += w.w * m.w;
      }
      float sdot = (a4.x + a4.y) + (a4.z + a4.w);
      sdot += __shfl_xor(sdot, 4, 64);   // reduce the 4 j-slices
      sdot += __shfl_xor(sdot, 8, 64);
      if (part == 0) {
        if (s <= 5) {
          int co = 1 + q * 6 + s;
          stg(&Mt[row * MTS + co], sdot); stg(&Mc[co * DD + row], sdot);
        } else if (q > 0) {
          stg(&Mc[(24 + q) * DD + row], sdot);   // cols 25..27, hop-only
        }
      }
      chain_bar(s);
    }
  } else {
    // ---------- everyone else: warm the embedding gather into L2/IC ----
    prefetch_tile(ctx_ids, emb, bid, tid);
    if (bid < 2 * (int)NCHAIN)
      prefetch_tile(ctx_ids, emb, bid - (int)NCHAIN, tid);  // chain's tiles
  }

  // ---------- gemm: tile = bid (64 ctx rows, wave = k-quarter) ---------
  {
    float* sw = sm.g.stag[wv];
    int myid = ctx_ids[rowbase + ln];
    const float* base[8];
#pragma unroll
    for (int ii = 0; ii < 8; ++ii) {
      int rid = __shfl(myid, ii * 8 + (ln >> 3), 64);
      base[ii] = emb + (size_t)rid * DD;
    }
    int p4 = (ln & 7) * 4;
    int k0 = wv * 256;
    float acc[25];
#pragma unroll
    for (int j = 0; j < 25; ++j) acc[j] = 0.f;

    // issue first-chunk loads BEFORE the chain wait (hide latency in spin)
    float4 buf[8];
#pragma unroll
    for (int ii = 0; ii < 8; ++ii)
      buf[ii] = *(const float4*)(base[ii] + k0 + p4);

    if (tid == 0) waitge(&g_c[5], NCHAIN * (E + 1u));  // cols 0..24 ready
    __syncthreads();

    for (int ch = 0; ch < 8; ++ch) {
#pragma unroll
      for (int ii = 0; ii < 8; ++ii) {
        int r = ii * 8 + (ln >> 3);
        int a = r * 33 + p4;
        sw[a + 0] = buf[ii].x; sw[a + 1] = buf[ii].y;
        sw[a + 2] = buf[ii].z; sw[a + 3] = buf[ii].w;
      }
      if (ch < 7) {
        int kb = k0 + (ch + 1) * 32;
#pragma unroll
        for (int ii = 0; ii < 8; ++ii)
          buf[ii] = *(const float4*)(base[ii] + kb + p4);
      }
      __builtin_amdgcn_s_waitcnt(0xc07f);  // lgkmcnt(0): same-wave LDS visibility
      const float* mrow = Mt + (size_t)(k0 + ch * 32) * MTS;  // wave-uniform
#pragma unroll 4
      for (int kk = 0; kk < 32; ++kk) {
        float mv = sw[ln * 33 + kk];
#pragma unroll
        for (int j = 0; j < 25; ++j) acc[j] += mv * mrow[kk * MTS + j];
      }
    }
#pragma unroll
    for (int j = 0; j < 25; ++j) sm.g.qp[wv][ln][j] = acc[j];
    __syncthreads();

    int b = rowbase >> 9;
    int l0 = rowbase & 511;
    int clen = ctx_len[b];
    int off = toff[b];
    float fclen = (float)clen;
    for (int i = tid; i < 1600; i += 256) {
      int j = i >> 6, r = i & 63;
      float s = sm.g.qp[0][r][j] + sm.g.qp[1][r][j] +
                sm.g.qp[2][r][j] + sm.g.qp[3][r][j];
      int l = l0 + r;
      float vl = (l < clen) ? (1.f - fabsf((float)(l - off)) / fclen) : 0.f;
      stg(&Q[((size_t)b * 25 + j) * LL + l], s * vl);
    }
  }
  __syncthreads();   // drains vmcnt: Q write-through stores at IC
  if (tid == 0)
    __hip_atomic_fetch_add(&g_q[bid >> 3], 1u, __ATOMIC_RELAXED,
                           __HIP_MEMORY_SCOPE_AGENT);

  // ---------- hop recursion: blocks 448..511 handle batch bid-448 ------
  if (bid < 448) return;
  {
    int b = bid - 448;
    if (tid == 0) {
      waitge(&g_q[b], 8u * (E + 1u));          // 8 Q producers of batch b
      waitge(&g_c[6], NCHAIN * (E + 1u));      // cols 25..27 (step 6)
    }
    __syncthreads();

    float* Qs = sm.h.Qs;
    float* va = sm.h.va;
    float* red = sm.h.red;

    for (int i = tid; i < 25 * LL; i += 256)
      Qs[i] = Q[(size_t)b * (25 * LL) + i];

    int tl = tgt_len[b];
    float inv_tl = 1.f / (float)tl;
    for (int d = tid; d < DD; d += 256) {
      float s = 0.f;
#pragma unroll
      for (int t = 0; t < 8; ++t)
        if (t < tl) s += emb[(size_t)tgt_ids[b * 8 + t] * DD + d];
      va[d] = s * inv_tl;
    }
    __syncthreads();

    // 32 dots: p[0..5]=va.U_k, p[6..8]=va.Y6c, p[9..13]=b.U_k(k<5), p[14+6c+k]=b.Y_{k,c}
    float p[32];
#pragma unroll
    for (int q = 0; q < 32; ++q) p[q] = 0.f;
    for (int d = tid; d < DD; d += 256) {
      float vad = va[d], bd = bl[d];
#pragma unroll
      for (int k = 0; k < 6; ++k) {
        float u = Mc[(1 + k) * DD + d];
        p[k] += vad * u;
        if (k < 5) p[9 + k] += bd * u;
      }
#pragma unroll
      for (int c = 0; c < 3; ++c) {
        p[6 + c] += vad * Mc[(25 + c) * DD + d];
#pragma unroll
        for (int k = 0; k < 6; ++k)
          p[14 + c * 6 + k] += bd * Mc[(7 + 6 * c + k) * DD + d];
      }
    }
    breduce<false>(p, 32, red, tid);

    float tcur[6], rc[3], beta[5], gam[18];
#pragma unroll
    for (int k = 0; k < 6; ++k) tcur[k] = p[k];
#pragma unroll
    for (int c = 0; c < 3; ++c) rc[c] = p[6 + c];
#pragma unroll
    for (int k = 0; k < 5; ++k) beta[k] = p[9 + k];
#pragma unroll
    for (int q = 0; q < 18; ++q) gam[q] = p[14 + q];

    int clen = ctx_len[b];
    float batt = bat[0];
    int l1 = tid, l2 = tid + 256;

    for (int h = 0; h < 6; ++h) {
      float s_h = tcur[0];
      float sc1 = -1e30f, sc2 = -1e30f;
      if (l1 < clen) sc1 = tanhf(Qs[l1] + s_h + batt);
      if (l2 < clen) sc2 = tanhf(Qs[l2] + s_h + batt);
      float mx = fmaxf(sc1, sc2);
      breduce<true>(&mx, 1, red, tid);

      float pe[9];
#pragma unroll
      for (int q = 0; q < 9; ++q) pe[q] = 0.f;
      int kd = 5 - h;
      if (l1 < clen) {
        float e = expf(sc1 - mx);
        pe[0] += e;
        for (int k = 0; k <= 4 - h; ++k) pe[1 + k] += e * Qs[(1 + k) * LL + l1];
#pragma unroll
        for (int c = 0; c < 3; ++c) pe[6 + c] += e * Qs[(7 + 6 * c + kd) * LL + l1];
      }
      if (l2 < clen) {
        float e = expf(sc2 - mx);
        pe[0] += e;
        for (int k = 0; k <= 4 - h; ++k) pe[1 + k] += e * Qs[(1 + k) * LL + l2];
#pragma unroll
        for (int c = 0; c < 3; ++c) pe[6 + c] += e * Qs[(7 + 6 * c + kd) * LL + l2];
      }
      breduce<false>(pe, 9, red, tid);

      float invS = 1.f / pe[0];
      for (int k = 0; k <= 4 - h; ++k)
        tcur[k] = pe[1 + k] * invS + tcur[k + 1] + beta[k];
#pragma unroll
      for (int c = 0; c < 3; ++c)
        rc[c] = pe[6 + c] * invS + rc[c] + gam[c * 6 + kd];
    }
    if (tid < 3) out[b * 3 + tid] = rc[tid] + bo[tid];
  }
}

extern "C" void kernel_launch(void* const* d_in, const int* in_sizes, int n_in,
                              void* d_out, int out_size, void* d_ws, size_t ws_size,
                              hipStream_t stream)
{
  const int*   ctx_ids = (const int*)d_in[0];
  const int*   tgt_ids = (const int*)d_in[1];
  const int*   ctx_len = (const int*)d_in[2];
  const int*   tgt_len = (const int*)d_in[3];
  const int*   toff    = (const int*)d_in[4];
  const float* emb     = (const float*)d_in[5];
  const float* Wl      = (const float*)d_in[6];
  const float* bl      = (const float*)d_in[7];
  const float* wat     = (const float*)d_in[8];
  const float* bat     = (const float*)d_in[9];
  const float* Wo      = (const float*)d_in[10];
  const float* bo      = (const float*)d_in[11];
  float* ws = (float*)d_ws;
  float* Mt = ws;                 // 1024*32
  float* Mc = ws + 32768;         // 32*1024
  float* Q  = ws + 65536;         // 64*25*512
  float* outp = (float*)d_out;

  hipLaunchKernelGGL(k_all, dim3(512), dim3(256), 0, stream,
                     ctx_ids, tgt_ids, ctx_len, tgt_len, toff, emb,
                     Wl, bl, wat, bat, bo, Wo, Mt, Mc, Q, outp);
}

// Round 6
// 468.164 us; speedup vs baseline: 1.0433x; 1.0433x over previous
//
#include <hip/hip_runtime.h>
#include <cstdint>

// MemNet, fully fused. Sync fabric v3: NO shared-line polling.
// Q[b,l,j] = v_loc[b,l] * (mem[b,l] . M_j),  25+3 projection columns:
//   col 0        : w0 = w_attn[0:D]
//   col 1+k      : U_k = W_lin^k u, k=0..5   (u = w_attn[D:2D])
//   col 7+6c+k   : Y_{k,c} = W_lin^k W_out[:,c], k=0..5
//   col 25+c     : Y_{6,c}  (hop phase only)
// Shared Mt/Mc/Q are WRITE-ONCE via agent-scope relaxed stores (write-
// through to the coherent point); no location read before its write in
// the dispatch -> no acquire/invalidate fences (validated rounds 4/5).
// Sync: producer __syncthreads drains write-through stores, then relaxed
// fetch_add arrival; LAST arriver fans out per-consumer padded flags;
// every spinner polls ITS OWN 128B-stride flag. This removes the
// single-cacheline poll storms that made rounds 2/4/5 sync-bound
// (512 pollers x 1 poll/0.35us serialized at the IC line).
// Phases: chain (64 blocks, flag mini-barriers) || emb prefetch (others)
//   -> per-block own-flag wait on chain step5 -> gemm (tile=bid)
//   -> per-batch g_q release -> hop blocks (448..511) wait 8 producers
//   + own g_r6 flag -> hop recursion.
// 512 blocks x 256 threads, 2 blocks/CU (LDS 59392 B, lb(256,2)); spins
// guard-bounded (fail loud, never hang). Epoch E = g_eb[bid]++ per block.

#define DD 1024
#define LL 512
#define MTS 32
#define NCHAIN 64
#define PAD 32   // one flag per 128B line

__device__ unsigned g_eb[512];            // per-block epoch counters
__device__ unsigned g_c[8];               // chain arrival counters (adds only)
__device__ unsigned g_cr[8][NCHAIN * PAD];// chain barrier release flags
__device__ unsigned g_r5[512 * PAD];      // step-5 release, one per block
__device__ unsigned g_r6[64 * PAD];       // step-6 release, one per hop block
__device__ unsigned g_q[64 * PAD];        // per-batch Q-ready counters

__device__ __forceinline__ void waitge(unsigned* p, unsigned tgt)
{
  int guard = 0;
  while (__hip_atomic_load(p, __ATOMIC_RELAXED, __HIP_MEMORY_SCOPE_AGENT) < tgt) {
    __builtin_amdgcn_s_sleep(1);
    if (++guard > (1 << 19)) break;   // fail loud, never hang
  }
}

// write-through (agent scope) relaxed stores: land at the coherent point
__device__ __forceinline__ void stg(float* p, float v) {
  __hip_atomic_store(p, v, __ATOMIC_RELAXED, __HIP_MEMORY_SCOPE_AGENT);
}
__device__ __forceinline__ void stgu(unsigned* p, unsigned v) {
  __hip_atomic_store(p, v, __ATOMIC_RELAXED, __HIP_MEMORY_SCOPE_AGENT);
}

// chain mini-barrier: last arriver fans out per-block flags; others poll own
__device__ __forceinline__ void chain_bar(int k, unsigned E, int bid)
{
  __syncthreads();   // drains vmcnt: all write-through stores at IC
  if (threadIdx.x == 0) {
    unsigned t = __hip_atomic_fetch_add(&g_c[k], 1u, __ATOMIC_RELAXED,
                                        __HIP_MEMORY_SCOPE_AGENT);
    if ((t % NCHAIN) == NCHAIN - 1) {       // last arrival this epoch
      for (int j = 0; j < NCHAIN; ++j) stgu(&g_cr[k][j * PAD], E + 1u);
    } else {
      waitge(&g_cr[k][bid * PAD], E + 1u);  // own line, zero contention
    }
  }
  __syncthreads();
}

union SMem {
  struct { float stag[4][64 * 33]; float qp[4][64][25]; } g;        // 59392 B
  struct { float Qs[25 * LL]; float va[DD]; float red[36 * 4]; } h; // 55872 B
};

__device__ __forceinline__ void keep4(float4 v) {
  asm volatile("" :: "v"(v.x), "v"(v.y), "v"(v.z), "v"(v.w));
}

// warm one 64-row tile (256 KB) of gathered embeddings into L2/IC,
// 16 loads in flight per wave
__device__ __forceinline__ void prefetch_tile(const int* __restrict__ ctx_ids,
                                              const float* __restrict__ emb,
                                              int tile, int tid)
{
  int ln = tid & 63;
  int myid = ctx_ids[tile * 64 + ln];
#pragma unroll
  for (int g = 0; g < 4; ++g) {
    float4 v[16];
#pragma unroll
    for (int rr = 0; rr < 16; ++rr) {
      int rid = __shfl(myid, g * 16 + rr, 64);
      v[rr] = ((const float4*)(emb + (size_t)rid * DD))[tid];
    }
#pragma unroll
    for (int rr = 0; rr < 16; ++rr) keep4(v[rr]);
  }
}

template <bool ISMAX>
__device__ __forceinline__ void breduce(float* v, int n, float* lds, int tid)
{
  int wv = __builtin_amdgcn_readfirstlane(tid >> 6);
  int ln = tid & 63;
  for (int q = 0; q < n; ++q) {
    float x = v[q];
#pragma unroll
    for (int m = 1; m < 64; m <<= 1) {
      float o = __shfl_xor(x, m, 64);
      x = ISMAX ? fmaxf(x, o) : x + o;
    }
    if (ln == 0) lds[q * 4 + wv] = x;
  }
  __syncthreads();
  for (int q = 0; q < n; ++q) {
    float a = lds[q * 4 + 0], b = lds[q * 4 + 1];
    float c = lds[q * 4 + 2], d = lds[q * 4 + 3];
    v[q] = ISMAX ? fmaxf(fmaxf(a, b), fmaxf(c, d)) : ((a + b) + (c + d));
  }
  __syncthreads();
}

__global__ __launch_bounds__(256, 2) void k_all(
    const int* __restrict__ ctx_ids, const int* __restrict__ tgt_ids,
    const int* __restrict__ ctx_len, const int* __restrict__ tgt_len,
    const int* __restrict__ toff,    const float* __restrict__ emb,
    const float* __restrict__ Wl,    const float* __restrict__ bl,
    const float* __restrict__ wat,   const float* __restrict__ bat,
    const float* __restrict__ bo,    const float* __restrict__ Wo,
    float* __restrict__ Mt, float* __restrict__ Mc,
    float* __restrict__ Q,  float* __restrict__ out)
{
  __shared__ SMem sm;
  __shared__ unsigned sE;
  const int tid = threadIdx.x;
  const int bid = blockIdx.x;
  const int wv  = __builtin_amdgcn_readfirstlane(tid >> 6);
  const int ln  = tid & 63;
  const int rowbase = bid * 64;

  unsigned E = 0;
  if (tid == 0) {
    E = __hip_atomic_fetch_add(&g_eb[bid], 1u, __ATOMIC_RELAXED,
                               __HIP_MEMORY_SCOPE_AGENT);
    sE = E;   // published to the block by the next __syncthreads
  }

  if (bid < NCHAIN) {
    // ---------- chain: init base columns, then 6 matvec steps -----------
    if (tid < 16) {
      int d = bid * 16 + tid;
      float w0 = wat[d], u0 = wat[DD + d];
      stg(&Mt[d * MTS + 0], w0); stg(&Mc[0 * DD + d], w0);
      stg(&Mt[d * MTS + 1], u0); stg(&Mc[1 * DD + d], u0);
#pragma unroll
      for (int c = 0; c < 3; ++c) {
        float y = Wo[d * 3 + c];
        int col = 7 + 6 * c;
        stg(&Mt[d * MTS + col], y); stg(&Mc[col * DD + d], y);
      }
    }
    chain_bar(0, E, bid);
    int g    = bid * 256 + tid;     // [0, 16384)
    int q    = g & 3;               // column group: 0=U, 1..3=Y_{c=q-1}
    int part = (g >> 2) & 3;        // j-slice [part*256, part*256+256)
    int row  = g >> 4;              // [0, 1024)
    const float* wr0 = Wl + (size_t)row * DD + part * 256;
    for (int s = 1; s <= 6; ++s) {
      int cin = (q == 0) ? s : q * 6 + s;
      const float* mc = Mc + (size_t)cin * DD + part * 256;
      float4 a4 = {0.f, 0.f, 0.f, 0.f};
#pragma unroll 8
      for (int j = 0; j < 256; j += 4) {
        float4 w = *(const float4*)(wr0 + j);
        float4 m = *(const float4*)(mc + j);
        a4.x += w.x * m.x; a4.y += w.y * m.y;
        a4.z += w.z * m.z; a4.w += w.w * m.w;
      }
      float sdot = (a4.x + a4.y) + (a4.z + a4.w);
      sdot += __shfl_xor(sdot, 4, 64);   // reduce the 4 j-slices
      sdot += __shfl_xor(sdot, 8, 64);
      if (part == 0) {
        if (s <= 5) {
          int co = 1 + q * 6 + s;
          stg(&Mt[row * MTS + co], sdot); stg(&Mc[co * DD + row], sdot);
        } else if (q > 0) {
          stg(&Mc[(24 + q) * DD + row], sdot);   // cols 25..27, hop-only
        }
      }
      chain_bar(s, E, bid);
      if (s == 5 && tid < 8)        // fan out step-5 release: 8 flags/block
        stgu(&g_r5[(bid * 8 + tid) * PAD], sE + 1u);
    }
    if (tid == 0) stgu(&g_r6[bid * PAD], E + 1u);   // step-6 release
  } else {
    // ---------- everyone else: warm the embedding gather into L2/IC ----
    prefetch_tile(ctx_ids, emb, bid, tid);
    if (bid < 2 * NCHAIN)
      prefetch_tile(ctx_ids, emb, bid - NCHAIN, tid);  // chain's tiles
  }

  // ---------- gemm: tile = bid (64 ctx rows, wave = k-quarter) ---------
  {
    float* sw = sm.g.stag[wv];
    int myid = ctx_ids[rowbase + ln];
    const float* base[8];
#pragma unroll
    for (int ii = 0; ii < 8; ++ii) {
      int rid = __shfl(myid, ii * 8 + (ln >> 3), 64);
      base[ii] = emb + (size_t)rid * DD;
    }
    int p4 = (ln & 7) * 4;
    int k0 = wv * 256;
    float acc[25];
#pragma unroll
    for (int j = 0; j < 25; ++j) acc[j] = 0.f;

    // issue first-chunk loads BEFORE the chain wait (hide latency in spin)
    float4 buf[8];
#pragma unroll
    for (int ii = 0; ii < 8; ++ii)
      buf[ii] = *(const float4*)(base[ii] + k0 + p4);

    if (bid >= NCHAIN && tid == 0)
      waitge(&g_r5[bid * PAD], E + 1u);   // own-line wait: cols 0..24 ready
    __syncthreads();

    for (int ch = 0; ch < 8; ++ch) {
#pragma unroll
      for (int ii = 0; ii < 8; ++ii) {
        int r = ii * 8 + (ln >> 3);
        int a = r * 33 + p4;
        sw[a + 0] = buf[ii].x; sw[a + 1] = buf[ii].y;
        sw[a + 2] = buf[ii].z; sw[a + 3] = buf[ii].w;
      }
      if (ch < 7) {
        int kb = k0 + (ch + 1) * 32;
#pragma unroll
        for (int ii = 0; ii < 8; ++ii)
          buf[ii] = *(const float4*)(base[ii] + kb + p4);
      }
      __builtin_amdgcn_s_waitcnt(0xc07f);  // lgkmcnt(0): same-wave LDS visibility
      const float* mrow = Mt + (size_t)(k0 + ch * 32) * MTS;  // wave-uniform
#pragma unroll 4
      for (int kk = 0; kk < 32; ++kk) {
        float mv = sw[ln * 33 + kk];
#pragma unroll
        for (int j = 0; j < 25; ++j) acc[j] += mv * mrow[kk * MTS + j];
      }
    }
#pragma unroll
    for (int j = 0; j < 25; ++j) sm.g.qp[wv][ln][j] = acc[j];
    __syncthreads();

    int b = rowbase >> 9;
    int l0 = rowbase & 511;
    int clen = ctx_len[b];
    int off = toff[b];
    float fclen = (float)clen;
    for (int i = tid; i < 1600; i += 256) {
      int j = i >> 6, r = i & 63;
      float s = sm.g.qp[0][r][j] + sm.g.qp[1][r][j] +
                sm.g.qp[2][r][j] + sm.g.qp[3][r][j];
      int l = l0 + r;
      float vl = (l < clen) ? (1.f - fabsf((float)(l - off)) / fclen) : 0.f;
      stg(&Q[((size_t)b * 25 + j) * LL + l], s * vl);
    }
  }
  __syncthreads();   // drains vmcnt: Q write-through stores at IC
  if (tid == 0)
    __hip_atomic_fetch_add(&g_q[(bid >> 3) * PAD], 1u, __ATOMIC_RELAXED,
                           __HIP_MEMORY_SCOPE_AGENT);

  // ---------- hop recursion: blocks 448..511 handle batch bid-448 ------
  if (bid < 448) return;
  {
    int b = bid - 448;
    if (tid == 0) {
      waitge(&g_q[b * PAD], 8u * (E + 1u));    // 8 Q producers of batch b
      waitge(&g_r6[b * PAD], E + 1u);          // cols 25..27 (step 6)
    }
    __syncthreads();

    float* Qs = sm.h.Qs;
    float* va = sm.h.va;
    float* red = sm.h.red;

    for (int i = tid; i < 25 * LL; i += 256)
      Qs[i] = Q[(size_t)b * (25 * LL) + i];

    int tl = tgt_len[b];
    float inv_tl = 1.f / (float)tl;
    for (int d = tid; d < DD; d += 256) {
      float s = 0.f;
#pragma unroll
      for (int t = 0; t < 8; ++t)
        if (t < tl) s += emb[(size_t)tgt_ids[b * 8 + t] * DD + d];
      va[d] = s * inv_tl;
    }
    __syncthreads();

    // 32 dots: p[0..5]=va.U_k, p[6..8]=va.Y6c, p[9..13]=b.U_k(k<5), p[14+6c+k]=b.Y_{k,c}
    float p[32];
#pragma unroll
    for (int q = 0; q < 32; ++q) p[q] = 0.f;
    for (int d = tid; d < DD; d += 256) {
      float vad = va[d], bd = bl[d];
#pragma unroll
      for (int k = 0; k < 6; ++k) {
        float u = Mc[(1 + k) * DD + d];
        p[k] += vad * u;
        if (k < 5) p[9 + k] += bd * u;
      }
#pragma unroll
      for (int c = 0; c < 3; ++c) {
        p[6 + c] += vad * Mc[(25 + c) * DD + d];
#pragma unroll
        for (int k = 0; k < 6; ++k)
          p[14 + c * 6 + k] += bd * Mc[(7 + 6 * c + k) * DD + d];
      }
    }
    breduce<false>(p, 32, red, tid);

    float tcur[6], rc[3], beta[5], gam[18];
#pragma unroll
    for (int k = 0; k < 6; ++k) tcur[k] = p[k];
#pragma unroll
    for (int c = 0; c < 3; ++c) rc[c] = p[6 + c];
#pragma unroll
    for (int k = 0; k < 5; ++k) beta[k] = p[9 + k];
#pragma unroll
    for (int q = 0; q < 18; ++q) gam[q] = p[14 + q];

    int clen = ctx_len[b];
    float batt = bat[0];
    int l1 = tid, l2 = tid + 256;

    for (int h = 0; h < 6; ++h) {
      float s_h = tcur[0];
      float sc1 = -1e30f, sc2 = -1e30f;
      if (l1 < clen) sc1 = tanhf(Qs[l1] + s_h + batt);
      if (l2 < clen) sc2 = tanhf(Qs[l2] + s_h + batt);
      float mx = fmaxf(sc1, sc2);
      breduce<true>(&mx, 1, red, tid);

      float pe[9];
#pragma unroll
      for (int q = 0; q < 9; ++q) pe[q] = 0.f;
      int kd = 5 - h;
      if (l1 < clen) {
        float e = expf(sc1 - mx);
        pe[0] += e;
        for (int k = 0; k <= 4 - h; ++k) pe[1 + k] += e * Qs[(1 + k) * LL + l1];
#pragma unroll
        for (int c = 0; c < 3; ++c) pe[6 + c] += e * Qs[(7 + 6 * c + kd) * LL + l1];
      }
      if (l2 < clen) {
        float e = expf(sc2 - mx);
        pe[0] += e;
        for (int k = 0; k <= 4 - h; ++k) pe[1 + k] += e * Qs[(1 + k) * LL + l2];
#pragma unroll
        for (int c = 0; c < 3; ++c) pe[6 + c] += e * Qs[(7 + 6 * c + kd) * LL + l2];
      }
      breduce<false>(pe, 9, red, tid);

      float invS = 1.f / pe[0];
      for (int k = 0; k <= 4 - h; ++k)
        tcur[k] = pe[1 + k] * invS + tcur[k + 1] + beta[k];
#pragma unroll
      for (int c = 0; c < 3; ++c)
        rc[c] = pe[6 + c] * invS + rc[c] + gam[c * 6 + kd];
    }
    if (tid < 3) out[b * 3 + tid] = rc[tid] + bo[tid];
  }
}

extern "C" void kernel_launch(void* const* d_in, const int* in_sizes, int n_in,
                              void* d_out, int out_size, void* d_ws, size_t ws_size,
                              hipStream_t stream)
{
  const int*   ctx_ids = (const int*)d_in[0];
  const int*   tgt_ids = (const int*)d_in[1];
  const int*   ctx_len = (const int*)d_in[2];
  const int*   tgt_len = (const int*)d_in[3];
  const int*   toff    = (const int*)d_in[4];
  const float* emb     = (const float*)d_in[5];
  const float* Wl      = (const float*)d_in[6];
  const float* bl      = (const float*)d_in[7];
  const float* wat     = (const float*)d_in[8];
  const float* bat     = (const float*)d_in[9];
  const float* Wo      = (const float*)d_in[10];
  const float* bo      = (const float*)d_in[11];
  float* ws = (float*)d_ws;
  float* Mt = ws;                 // 1024*32
  float* Mc = ws + 32768;         // 32*1024
  float* Q  = ws + 65536;         // 64*25*512
  float* outp = (float*)d_out;

  hipLaunchKernelGGL(k_all, dim3(512), dim3(256), 0, stream,
                     ctx_ids, tgt_ids, ctx_len, tgt_len, toff, emb,
                     Wl, bl, wat, bat, bo, Wo, Mt, Mc, Q, outp);
}

// Round 8
// 466.084 us; speedup vs baseline: 1.0479x; 1.0045x over previous
//
#include <hip/hip_runtime.h>
#include <cstdint>

// MemNet, fully fused. Sync fabric v3 (padded per-consumer flags, no
// shared-line polling). Gather strategy v2: NO prefetch herd -- the
// 134 MB embedding gather is paced through the gemm itself with a
// 4-deep register pipeline (32 loads in flight per thread), issued
// BEFORE the chain-flag spin so the chain hides under the gather.
// (Round 6 post-mortem: prefetch doubled the gather, self-thrashed
// the 4MB/XCD L2s 4x over, and was the ~100us regression vs unfused.)
// Round 8 = round 7 resubmitted verbatim after an infra-level
// "container failed twice" (same flake as round 3; kernel audited clean).
//
// Q[b,l,j] = v_loc[b,l] * (mem[b,l] . M_j),  25+3 projection columns:
//   col 0        : w0 = w_attn[0:D]
//   col 1+k      : U_k = W_lin^k u, k=0..5   (u = w_attn[D:2D])
//   col 7+6c+k   : Y_{k,c} = W_lin^k W_out[:,c], k=0..5
//   col 25+c     : Y_{6,c}  (hop phase only)
// Shared Mt/Mc/Q are WRITE-ONCE via agent-scope relaxed stores (write-
// through to the coherent point); no location read before its write in
// the dispatch -> no acquire/invalidate fences (validated rounds 4-6).
// Phases: chain (64 blocks, flag mini-barriers) -> per-block own-flag
// wait on chain step5 -> gemm (tile=bid) -> per-batch g_q release ->
// hop blocks (448..511) wait 8 producers + own g_r6 flag -> recursion.
// 512 blocks x 256 threads, 2 blocks/CU (LDS 59392 B, lb(256,2)); spins
// guard-bounded (fail loud, never hang). Epoch E = g_eb[bid]++ per block.

#define DD 1024
#define LL 512
#define MTS 32
#define NCHAIN 64
#define PAD 32   // one flag per 128B line

__device__ unsigned g_eb[512];            // per-block epoch counters
__device__ unsigned g_c[8];               // chain arrival counters (adds only)
__device__ unsigned g_cr[8][NCHAIN * PAD];// chain barrier release flags
__device__ unsigned g_r5[512 * PAD];      // step-5 release, one per block
__device__ unsigned g_r6[64 * PAD];       // step-6 release, one per hop block
__device__ unsigned g_q[64 * PAD];        // per-batch Q-ready counters

__device__ __forceinline__ void waitge(unsigned* p, unsigned tgt)
{
  int guard = 0;
  while (__hip_atomic_load(p, __ATOMIC_RELAXED, __HIP_MEMORY_SCOPE_AGENT) < tgt) {
    __builtin_amdgcn_s_sleep(1);
    if (++guard > (1 << 19)) break;   // fail loud, never hang
  }
}

// write-through (agent scope) relaxed stores: land at the coherent point
__device__ __forceinline__ void stg(float* p, float v) {
  __hip_atomic_store(p, v, __ATOMIC_RELAXED, __HIP_MEMORY_SCOPE_AGENT);
}
__device__ __forceinline__ void stgu(unsigned* p, unsigned v) {
  __hip_atomic_store(p, v, __ATOMIC_RELAXED, __HIP_MEMORY_SCOPE_AGENT);
}

// chain mini-barrier: last arriver fans out per-block flags; others poll own
__device__ __forceinline__ void chain_bar(int k, unsigned E, int bid)
{
  __syncthreads();   // drains vmcnt: all write-through stores at IC
  if (threadIdx.x == 0) {
    unsigned t = __hip_atomic_fetch_add(&g_c[k], 1u, __ATOMIC_RELAXED,
                                        __HIP_MEMORY_SCOPE_AGENT);
    if ((t % NCHAIN) == NCHAIN - 1) {       // last arrival this epoch
      for (int j = 0; j < NCHAIN; ++j) stgu(&g_cr[k][j * PAD], E + 1u);
    } else {
      waitge(&g_cr[k][bid * PAD], E + 1u);  // own line, zero contention
    }
  }
  __syncthreads();
}

union SMem {
  struct { float stag[4][64 * 33]; float qp[4][64][25]; } g;        // 59392 B
  struct { float Qs[25 * LL]; float va[DD]; float red[36 * 4]; } h; // 55872 B
};

template <bool ISMAX>
__device__ __forceinline__ void breduce(float* v, int n, float* lds, int tid)
{
  int wv = __builtin_amdgcn_readfirstlane(tid >> 6);
  int ln = tid & 63;
  for (int q = 0; q < n; ++q) {
    float x = v[q];
#pragma unroll
    for (int m = 1; m < 64; m <<= 1) {
      float o = __shfl_xor(x, m, 64);
      x = ISMAX ? fmaxf(x, o) : x + o;
    }
    if (ln == 0) lds[q * 4 + wv] = x;
  }
  __syncthreads();
  for (int q = 0; q < n; ++q) {
    float a = lds[q * 4 + 0], b = lds[q * 4 + 1];
    float c = lds[q * 4 + 2], d = lds[q * 4 + 3];
    v[q] = ISMAX ? fmaxf(fmaxf(a, b), fmaxf(c, d)) : ((a + b) + (c + d));
  }
  __syncthreads();
}

__global__ __launch_bounds__(256, 2) void k_all(
    const int* __restrict__ ctx_ids, const int* __restrict__ tgt_ids,
    const int* __restrict__ ctx_len, const int* __restrict__ tgt_len,
    const int* __restrict__ toff,    const float* __restrict__ emb,
    const float* __restrict__ Wl,    const float* __restrict__ bl,
    const float* __restrict__ wat,   const float* __restrict__ bat,
    const float* __restrict__ bo,    const float* __restrict__ Wo,
    float* __restrict__ Mt, float* __restrict__ Mc,
    float* __restrict__ Q,  float* __restrict__ out)
{
  __shared__ SMem sm;
  __shared__ unsigned sE;
  const int tid = threadIdx.x;
  const int bid = blockIdx.x;
  const int wv  = __builtin_amdgcn_readfirstlane(tid >> 6);
  const int ln  = tid & 63;
  const int rowbase = bid * 64;

  unsigned E = 0;
  if (tid == 0) {
    E = __hip_atomic_fetch_add(&g_eb[bid], 1u, __ATOMIC_RELAXED,
                               __HIP_MEMORY_SCOPE_AGENT);
    sE = E;   // published to the block by the next __syncthreads
  }

  if (bid < NCHAIN) {
    // ---------- chain: init base columns, then 6 matvec steps -----------
    if (tid < 16) {
      int d = bid * 16 + tid;
      float w0 = wat[d], u0 = wat[DD + d];
      stg(&Mt[d * MTS + 0], w0); stg(&Mc[0 * DD + d], w0);
      stg(&Mt[d * MTS + 1], u0); stg(&Mc[1 * DD + d], u0);
#pragma unroll
      for (int c = 0; c < 3; ++c) {
        float y = Wo[d * 3 + c];
        int col = 7 + 6 * c;
        stg(&Mt[d * MTS + col], y); stg(&Mc[col * DD + d], y);
      }
    }
    chain_bar(0, E, bid);
    int g    = bid * 256 + tid;     // [0, 16384)
    int q    = g & 3;               // column group: 0=U, 1..3=Y_{c=q-1}
    int part = (g >> 2) & 3;        // j-slice [part*256, part*256+256)
    int row  = g >> 4;              // [0, 1024)
    const float* wr0 = Wl + (size_t)row * DD + part * 256;
    for (int s = 1; s <= 6; ++s) {
      int cin = (q == 0) ? s : q * 6 + s;
      const float* mc = Mc + (size_t)cin * DD + part * 256;
      float4 a4 = {0.f, 0.f, 0.f, 0.f};
#pragma unroll 8
      for (int j = 0; j < 256; j += 4) {
        float4 w = *(const float4*)(wr0 + j);
        float4 m = *(const float4*)(mc + j);
        a4.x += w.x * m.x; a4.y += w.y * m.y;
        a4.z += w.z * m.z; a4.w += w.w * m.w;
      }
      float sdot = (a4.x + a4.y) + (a4.z + a4.w);
      sdot += __shfl_xor(sdot, 4, 64);   // reduce the 4 j-slices
      sdot += __shfl_xor(sdot, 8, 64);
      if (part == 0) {
        if (s <= 5) {
          int co = 1 + q * 6 + s;
          stg(&Mt[row * MTS + co], sdot); stg(&Mc[co * DD + row], sdot);
        } else if (q > 0) {
          stg(&Mc[(24 + q) * DD + row], sdot);   // cols 25..27, hop-only
        }
      }
      chain_bar(s, E, bid);
      if (s == 5 && tid < 8)        // fan out step-5 release: 8 flags/block
        stgu(&g_r5[(bid * 8 + tid) * PAD], sE + 1u);
    }
    if (tid == 0) stgu(&g_r6[bid * PAD], E + 1u);   // step-6 release
  }

  // ---------- gemm: tile = bid (64 ctx rows, wave = k-quarter) ---------
  // 4-deep register pipeline: 32 loads in flight per thread; first 4
  // chunks issued BEFORE the chain-flag spin so half the tile's HBM
  // traffic drains under the chain phase.
  {
    float* sw = sm.g.stag[wv];
    int myid = ctx_ids[rowbase + ln];
    const float* base[8];
#pragma unroll
    for (int ii = 0; ii < 8; ++ii) {
      int rid = __shfl(myid, ii * 8 + (ln >> 3), 64);
      base[ii] = emb + (size_t)rid * DD;
    }
    int p4 = (ln & 7) * 4;
    int k0 = wv * 256;
    float acc[25];
#pragma unroll
    for (int j = 0; j < 25; ++j) acc[j] = 0.f;

    float4 bA[8], bB[8], bC[8], bD[8];

#define LOADB(BUF, CH)                                                  \
    _Pragma("unroll")                                                   \
    for (int ii = 0; ii < 8; ++ii)                                      \
      BUF[ii] = *(const float4*)(base[ii] + k0 + (CH) * 32 + p4);

#define STAGEB(BUF)                                                     \
    _Pragma("unroll")                                                   \
    for (int ii = 0; ii < 8; ++ii) {                                    \
      int a = (ii * 8 + (ln >> 3)) * 33 + p4;                           \
      sw[a + 0] = BUF[ii].x; sw[a + 1] = BUF[ii].y;                     \
      sw[a + 2] = BUF[ii].z; sw[a + 3] = BUF[ii].w;                     \
    }

#define COMPC(CH) {                                                     \
    __builtin_amdgcn_s_waitcnt(0xc07f); /* lgkmcnt(0) */                \
    const float* mrow = Mt + (size_t)(k0 + (CH) * 32) * MTS;            \
    _Pragma("unroll 4")                                                 \
    for (int kk = 0; kk < 32; ++kk) {                                   \
      float mv = sw[ln * 33 + kk];                                      \
      _Pragma("unroll")                                                 \
      for (int j = 0; j < 25; ++j) acc[j] += mv * mrow[kk * MTS + j];   \
    } }

    LOADB(bA, 0) LOADB(bB, 1) LOADB(bC, 2) LOADB(bD, 3)

    if (bid >= NCHAIN && tid == 0)
      waitge(&g_r5[bid * PAD], E + 1u);   // own-line wait: cols 0..24 ready
    __syncthreads();

    STAGEB(bA) LOADB(bA, 4) COMPC(0)
    STAGEB(bB) LOADB(bB, 5) COMPC(1)
    STAGEB(bC) LOADB(bC, 6) COMPC(2)
    STAGEB(bD) LOADB(bD, 7) COMPC(3)
    STAGEB(bA) COMPC(4)
    STAGEB(bB) COMPC(5)
    STAGEB(bC) COMPC(6)
    STAGEB(bD) COMPC(7)

#undef LOADB
#undef STAGEB
#undef COMPC

#pragma unroll
    for (int j = 0; j < 25; ++j) sm.g.qp[wv][ln][j] = acc[j];
    __syncthreads();

    int b = rowbase >> 9;
    int l0 = rowbase & 511;
    int clen = ctx_len[b];
    int off = toff[b];
    float fclen = (float)clen;
    for (int i = tid; i < 1600; i += 256) {
      int j = i >> 6, r = i & 63;
      float s = sm.g.qp[0][r][j] + sm.g.qp[1][r][j] +
                sm.g.qp[2][r][j] + sm.g.qp[3][r][j];
      int l = l0 + r;
      float vl = (l < clen) ? (1.f - fabsf((float)(l - off)) / fclen) : 0.f;
      stg(&Q[((size_t)b * 25 + j) * LL + l], s * vl);
    }
  }
  __syncthreads();   // drains vmcnt: Q write-through stores at IC
  if (tid == 0)
    __hip_atomic_fetch_add(&g_q[(bid >> 3) * PAD], 1u, __ATOMIC_RELAXED,
                           __HIP_MEMORY_SCOPE_AGENT);

  // ---------- hop recursion: blocks 448..511 handle batch bid-448 ------
  if (bid < 448) return;
  {
    int b = bid - 448;
    if (tid == 0) {
      waitge(&g_q[b * PAD], 8u * (E + 1u));    // 8 Q producers of batch b
      waitge(&g_r6[b * PAD], E + 1u);          // cols 25..27 (step 6)
    }
    __syncthreads();

    float* Qs = sm.h.Qs;
    float* va = sm.h.va;
    float* red = sm.h.red;

    for (int i = tid; i < 25 * LL; i += 256)
      Qs[i] = Q[(size_t)b * (25 * LL) + i];

    int tl = tgt_len[b];
    float inv_tl = 1.f / (float)tl;
    for (int d = tid; d < DD; d += 256) {
      float s = 0.f;
#pragma unroll
      for (int t = 0; t < 8; ++t)
        if (t < tl) s += emb[(size_t)tgt_ids[b * 8 + t] * DD + d];
      va[d] = s * inv_tl;
    }
    __syncthreads();

    // 32 dots: p[0..5]=va.U_k, p[6..8]=va.Y6c, p[9..13]=b.U_k(k<5), p[14+6c+k]=b.Y_{k,c}
    float p[32];
#pragma unroll
    for (int q = 0; q < 32; ++q) p[q] = 0.f;
    for (int d = tid; d < DD; d += 256) {
      float vad = va[d], bd = bl[d];
#pragma unroll
      for (int k = 0; k < 6; ++k) {
        float u = Mc[(1 + k) * DD + d];
        p[k] += vad * u;
        if (k < 5) p[9 + k] += bd * u;
      }
#pragma unroll
      for (int c = 0; c < 3; ++c) {
        p[6 + c] += vad * Mc[(25 + c) * DD + d];
#pragma unroll
        for (int k = 0; k < 6; ++k)
          p[14 + c * 6 + k] += bd * Mc[(7 + 6 * c + k) * DD + d];
      }
    }
    breduce<false>(p, 32, red, tid);

    float tcur[6], rc[3], beta[5], gam[18];
#pragma unroll
    for (int k = 0; k < 6; ++k) tcur[k] = p[k];
#pragma unroll
    for (int c = 0; c < 3; ++c) rc[c] = p[6 + c];
#pragma unroll
    for (int k = 0; k < 5; ++k) beta[k] = p[9 + k];
#pragma unroll
    for (int q = 0; q < 18; ++q) gam[q] = p[14 + q];

    int clen = ctx_len[b];
    float batt = bat[0];
    int l1 = tid, l2 = tid + 256;

    for (int h = 0; h < 6; ++h) {
      float s_h = tcur[0];
      float sc1 = -1e30f, sc2 = -1e30f;
      if (l1 < clen) sc1 = tanhf(Qs[l1] + s_h + batt);
      if (l2 < clen) sc2 = tanhf(Qs[l2] + s_h + batt);
      float mx = fmaxf(sc1, sc2);
      breduce<true>(&mx, 1, red, tid);

      float pe[9];
#pragma unroll
      for (int q = 0; q < 9; ++q) pe[q] = 0.f;
      int kd = 5 - h;
      if (l1 < clen) {
        float e = expf(sc1 - mx);
        pe[0] += e;
        for (int k = 0; k <= 4 - h; ++k) pe[1 + k] += e * Qs[(1 + k) * LL + l1];
#pragma unroll
        for (int c = 0; c < 3; ++c) pe[6 + c] += e * Qs[(7 + 6 * c + kd) * LL + l1];
      }
      if (l2 < clen) {
        float e = expf(sc2 - mx);
        pe[0] += e;
        for (int k = 0; k <= 4 - h; ++k) pe[1 + k] += e * Qs[(1 + k) * LL + l2];
#pragma unroll
        for (int c = 0; c < 3; ++c) pe[6 + c] += e * Qs[(7 + 6 * c + kd) * LL + l2];
      }
      breduce<false>(pe, 9, red, tid);

      float invS = 1.f / pe[0];
      for (int k = 0; k <= 4 - h; ++k)
        tcur[k] = pe[1 + k] * invS + tcur[k + 1] + beta[k];
#pragma unroll
      for (int c = 0; c < 3; ++c)
        rc[c] = pe[6 + c] * invS + rc[c] + gam[c * 6 + kd];
    }
    if (tid < 3) out[b * 3 + tid] = rc[tid] + bo[tid];
  }
}

extern "C" void kernel_launch(void* const* d_in, const int* in_sizes, int n_in,
                              void* d_out, int out_size, void* d_ws, size_t ws_size,
                              hipStream_t stream)
{
  const int*   ctx_ids = (const int*)d_in[0];
  const int*   tgt_ids = (const int*)d_in[1];
  const int*   ctx_len = (const int*)d_in[2];
  const int*   tgt_len = (const int*)d_in[3];
  const int*   toff    = (const int*)d_in[4];
  const float* emb     = (const float*)d_in[5];
  const float* Wl      = (const float*)d_in[6];
  const float* bl      = (const float*)d_in[7];
  const float* wat     = (const float*)d_in[8];
  const float* bat     = (const float*)d_in[9];
  const float* Wo      = (const float*)d_in[10];
  const float* bo      = (const float*)d_in[11];
  float* ws = (float*)d_ws;
  float* Mt = ws;                 // 1024*32
  float* Mc = ws + 32768;         // 32*1024
  float* Q  = ws + 65536;         // 64*25*512
  float* outp = (float*)d_out;

  hipLaunchKernelGGL(k_all, dim3(512), dim3(256), 0, stream,
                     ctx_ids, tgt_ids, ctx_len, tgt_len, toff, emb,
                     Wl, bl, wat, bat, bo, Wo, Mt, Mc, Q, outp);
}